// Round 15
// baseline (444.053 us; speedup 1.0000x reference)
//
#include <hip/hip_runtime.h>
#include <hip/hip_fp16.h>
#include <cstdint>
#include <cstddef>

#define N_NODES 100000
#define N_EDGES 1600000
#define BSH 6
#define BNODES 64
#define NB 1563          // ceil(100000/64)
#define LDK 136          // LDS tile row stride in halves (272 B)

typedef _Float16 f16x8 __attribute__((ext_vector_type(8)));
typedef float f32x4 __attribute__((ext_vector_type(4)));

// ---------------- fp16 helpers ----------------

__device__ __forceinline__ float h2f(ushort u) {
    __half_raw r;
    r.x = u;
    return __half2float(__half(r));
}

__device__ __forceinline__ ushort f2h(float f) {
    __half h = __float2half(f);
    return static_cast<__half_raw>(h).x;
}

// ---------------- fused prep: bucket count + cast x + PACK weights ----------------
// Packed weight layout per matrix (C cols): flat o = ((nf*4 + kg)*64 + lane)*8 + j
// holds W[k][c] with k = kg*32 + (lane>>4)*8 + j, c = nf*16 + (lane&15).

__global__ __launch_bounds__(256) void prep_all(
        const int* __restrict__ dst, int* __restrict__ bcnt, int E,
        const float* __restrict__ x, ushort* __restrict__ x_f16, int n4,
        const float* __restrict__ W1l, const float* __restrict__ W1r,
        const float* __restrict__ W2l, const float* __restrict__ W2r,
        const float* __restrict__ Wm,
        ushort* __restrict__ W1lP, ushort* __restrict__ W1rP,
        ushort* __restrict__ W2lP, ushort* __restrict__ W2rP,
        ushort* __restrict__ WmP) {
    int bid = blockIdx.x;
    if (bid < 256) {
        __shared__ int lh[NB];
        for (int i = threadIdx.x; i < NB; i += 256) lh[i] = 0;
        __syncthreads();
        for (int e = bid * 256 + threadIdx.x; e < E; e += 256 * 256)
            atomicAdd(&lh[dst[e] >> BSH], 1);
        __syncthreads();
        for (int i = threadIdx.x; i < NB; i += 256) {
            int v = lh[i];
            if (v) atomicAdd(&bcnt[i], v);
        }
    } else if (bid < 256 + 12500) {
        int i = (bid - 256) * 256 + threadIdx.x;
        if (i < n4) {
            float4 v = reinterpret_cast<const float4*>(x)[i];
            ushort4 o;
            o.x = f2h(v.x);
            o.y = f2h(v.y);
            o.z = f2h(v.z);
            o.w = f2h(v.w);
            reinterpret_cast<ushort4*>(x_f16)[i] = o;
        }
    } else {
        int t = (bid - (256 + 12500)) * 256 + threadIdx.x;
        if (t < 65536) {            // 4 matrices of 128x128
            int wsel = t >> 14;
            int o = t & 16383;
            const float* srcs[4] = {W1l, W1r, W2l, W2r};
            ushort* dsts[4] = {W1lP, W1rP, W2lP, W2rP};
            int j = o & 7;
            int lane = (o >> 3) & 63;
            int kg = (o >> 9) & 3;
            int nf = o >> 11;
            int k = kg * 32 + (lane >> 4) * 8 + j;
            int c = nf * 16 + (lane & 15);
            dsts[wsel][o] = f2h(srcs[wsel][k * 128 + c]);
        } else if (t < 65536 + 8192) {  // Wm: 128x64
            int o = t - 65536;
            int j = o & 7;
            int lane = (o >> 3) & 63;
            int kg = (o >> 9) & 3;
            int nf = o >> 11;           // < 4
            int k = kg * 32 + (lane >> 4) * 8 + j;
            int c = nf * 16 + (lane & 15);
            WmP[o] = f2h(Wm[k * 64 + c]);
        }
    }
}

// single-block exclusive scan over NB elements
__global__ void scan_buckets(const int* __restrict__ bcnt, int* __restrict__ boffs) {
    __shared__ int sdata[256];
    int tid = threadIdx.x;
    int v[8];
    int s = 0;
#pragma unroll
    for (int i = 0; i < 8; i++) {
        int idx = tid * 8 + i;
        v[i] = (idx < NB) ? bcnt[idx] : 0;
        s += v[i];
    }
    sdata[tid] = s;
    __syncthreads();
    int acc = s;
    for (int off = 1; off < 256; off <<= 1) {
        int t = (tid >= off) ? sdata[tid - off] : 0;
        __syncthreads();
        acc += t;
        sdata[tid] = acc;
        __syncthreads();
    }
    int excl = acc - s;
#pragma unroll
    for (int i = 0; i < 8; i++) {
        int idx = tid * 8 + i;
        if (idx < NB) boffs[idx] = excl;
        excl += v[i];
    }
}

// scatter edges into bucket regions as packed (dstLocal<<17 | src)
__global__ void bucket_scatter(const int* __restrict__ src, const int* __restrict__ dst,
                               const int* __restrict__ boffs, int* __restrict__ gcur,
                               uint* __restrict__ bedges, int E) {
    __shared__ int lh[NB];
    __shared__ int lbase[NB];
    int nwg = gridDim.x;
    int chunk = (E + nwg - 1) / nwg;
    int e0 = blockIdx.x * chunk;
    int e1 = e0 + chunk;
    if (e1 > E) e1 = E;
    for (int i = threadIdx.x; i < NB; i += 256) lh[i] = 0;
    __syncthreads();
    for (int e = e0 + threadIdx.x; e < e1; e += 256)
        atomicAdd(&lh[dst[e] >> BSH], 1);
    __syncthreads();
    for (int i = threadIdx.x; i < NB; i += 256) {
        int v = lh[i];
        lbase[i] = v ? (boffs[i] + atomicAdd(&gcur[i], v)) : 0;
    }
    __syncthreads();
    for (int i = threadIdx.x; i < NB; i += 256) lh[i] = 0;  // reuse as local cursor
    __syncthreads();
    int e = e0 + threadIdx.x;
#pragma unroll 1
    for (; e + 3 * 256 < e1; e += 4 * 256) {
        int d0 = dst[e + 0 * 256], s0 = src[e + 0 * 256];
        int d1 = dst[e + 1 * 256], s1 = src[e + 1 * 256];
        int d2 = dst[e + 2 * 256], s2 = src[e + 2 * 256];
        int d3 = dst[e + 3 * 256], s3 = src[e + 3 * 256];
        int b0 = d0 >> BSH, b1 = d1 >> BSH, b2 = d2 >> BSH, b3 = d3 >> BSH;
        int r0 = atomicAdd(&lh[b0], 1);
        int r1 = atomicAdd(&lh[b1], 1);
        int r2 = atomicAdd(&lh[b2], 1);
        int r3 = atomicAdd(&lh[b3], 1);
        bedges[lbase[b0] + r0] = ((uint)(d0 & (BNODES - 1)) << 17) | (uint)s0;
        bedges[lbase[b1] + r1] = ((uint)(d1 & (BNODES - 1)) << 17) | (uint)s1;
        bedges[lbase[b2] + r2] = ((uint)(d2 & (BNODES - 1)) << 17) | (uint)s2;
        bedges[lbase[b3] + r3] = ((uint)(d3 & (BNODES - 1)) << 17) | (uint)s3;
    }
    for (; e < e1; e += 256) {
        int d = dst[e];
        int b = d >> BSH;
        int r = atomicAdd(&lh[b], 1);
        bedges[lbase[b] + r] = ((uint)(d & (BNODES - 1)) << 17) | (uint)src[e];
    }
}

// ---------------- one-time per-bucket sort: node-ordered src lists ----------------
// Histogram-only (no LDS edge storage -> no bucket-size limit). Produces
// srcs_sorted (grouped by dst node), noffs[node] (absolute), ncnt[node].

__global__ __launch_bounds__(256) void sort_buckets(
        const uint* __restrict__ bedges, const int* __restrict__ boffs,
        const int* __restrict__ bcnt, uint* __restrict__ srcs_sorted,
        int* __restrict__ noffs, int* __restrict__ ncnt, int n) {
    __shared__ int lh[BNODES];
    __shared__ int lofs[BNODES];
    int b = blockIdx.x;
    int beg = boffs[b];
    int m = bcnt[b];
    int node0 = b << BSH;
    int tid = threadIdx.x;
    if (tid < BNODES) lh[tid] = 0;
    __syncthreads();
    for (int i = tid; i < m; i += 256)
        atomicAdd(&lh[bedges[beg + i] >> 17], 1);
    __syncthreads();
    if (tid < BNODES) {   // wave 0: inclusive scan
        int v = lh[tid];
        int s = v;
#pragma unroll
        for (int off = 1; off < 64; off <<= 1) {
            int t = __shfl_up(s, off);
            if (tid >= off) s += t;
        }
        lofs[tid] = s - v;   // exclusive
        if (node0 + tid < n) {
            noffs[node0 + tid] = beg + s - v;
            ncnt[node0 + tid] = v;
        }
        lh[tid] = 0;         // reuse as cursor
    }
    __syncthreads();
    for (int i = tid; i < m; i += 256) {
        uint p = bedges[beg + i];
        int k = p >> 17;
        int r = atomicAdd(&lh[k], 1);
        srcs_sorted[beg + lofs[k] + r] = p & 0x1FFFFu;
    }
}

// ---------------- XCD-sliced mean aggregation ----------------
// Grid = NB*4; blockIdx = b*4 + s. Slice s covers channels [s*32, s*32+32)
// (one 64B cache line per node row). Under blockIdx%8 XCD round-robin,
// slice s lands only on XCDs {s, s+4} -> per-XCD L2 only fills its slice.
// 4 waves x 16 nodes; 4 lane-groups of 16 process alternating edges;
// lane covers 2 channels (uint fp16 pair). No LDS, no barriers.

__global__ __launch_bounds__(256) void aggregate_sliced(
        const ushort* __restrict__ F, const uint* __restrict__ srcs,
        const int* __restrict__ noffs, const int* __restrict__ ncnt,
        ushort* __restrict__ out, int n) {
    int bi = blockIdx.x;
    int b = bi >> 2;
    int s = bi & 3;
    int w = threadIdx.x >> 6;
    int lane = threadIdx.x & 63;
    int g = lane >> 4;       // edge group
    int cl = lane & 15;      // channel pair slot
    const ushort* Fs = F + s * 32 + cl * 2;
#pragma unroll 1
    for (int ki = 0; ki < 16; ki++) {
        int node = (b << BSH) + w * 16 + ki;
        if (node >= n) continue;
        int o = noffs[node];
        int c = ncnt[node];
        float ax = 0.f, ay = 0.f;
        int j = g;
        for (; j + 4 < c; j += 8) {
            uint s0 = srcs[o + j];
            uint s1 = srcs[o + j + 4];
            uint v0 = *reinterpret_cast<const uint*>(Fs + (size_t)s0 * 128);
            uint v1 = *reinterpret_cast<const uint*>(Fs + (size_t)s1 * 128);
            ax += h2f((ushort)(v0 & 0xffff)) + h2f((ushort)(v1 & 0xffff));
            ay += h2f((ushort)(v0 >> 16)) + h2f((ushort)(v1 >> 16));
        }
        if (j < c) {
            uint s0 = srcs[o + j];
            uint v0 = *reinterpret_cast<const uint*>(Fs + (size_t)s0 * 128);
            ax += h2f((ushort)(v0 & 0xffff));
            ay += h2f((ushort)(v0 >> 16));
        }
        ax += __shfl_xor(ax, 16);
        ay += __shfl_xor(ay, 16);
        ax += __shfl_xor(ax, 32);
        ay += __shfl_xor(ay, 32);
        if (g == 0) {
            float inv = 1.0f / fmaxf((float)c, 1.0f);
            uint o2 = (uint)f2h(ax * inv) | ((uint)f2h(ay * inv) << 16);
            *reinterpret_cast<uint*>(out + (size_t)node * 128 + s * 32 + cl * 2) = o2;
        }
    }
}

// ---------------- MFMA GEMM layer 1: 16-row waves, packed weights ----------------

__global__ __launch_bounds__(256) void gemm1(
        const ushort* __restrict__ A1, const ushort* __restrict__ W1lP,
        const ushort* __restrict__ A2, const ushort* __restrict__ W1rP,
        const float* __restrict__ b1, ushort* __restrict__ h_f16, int n) {
    __shared__ ushort ht[64 * LDK];   // 17.4 KB h fp16 tile
    int wid = threadIdx.x >> 6;
    int lane = threadIdx.x & 63;
    int row0 = blockIdx.x * 64 + wid * 16;
    int fr = lane & 15;
    int ko = (lane >> 4) * 8;
    int arow = row0 + fr;
    if (arow >= n) arow = n - 1;

    f32x4 acc[8];
#pragma unroll
    for (int nf = 0; nf < 8; nf++) acc[nf] = (f32x4)0.f;

    for (int seg = 0; seg < 2; ++seg) {
        const ushort* A = seg ? A2 : A1;
        const ushort* WP = seg ? W1rP : W1lP;
#pragma unroll
        for (int kg = 0; kg < 4; kg++) {
            f16x8 av = *reinterpret_cast<const f16x8*>(A + (size_t)arow * 128 + kg * 32 + ko);
#pragma unroll
            for (int nf = 0; nf < 8; nf++) {
                f16x8 bv = *reinterpret_cast<const f16x8*>(WP + (nf * 4 + kg) * 512 + lane * 8);
                acc[nf] = __builtin_amdgcn_mfma_f32_16x16x32_f16(av, bv, acc[nf], 0, 0, 0);
            }
        }
    }

    int crow = (lane >> 4) * 4;
    int ccol = lane & 15;
#pragma unroll
    for (int reg = 0; reg < 4; reg++) {
        int lrow = wid * 16 + crow + reg;
#pragma unroll
        for (int nf = 0; nf < 8; nf++) {
            float v = acc[nf][reg] + b1[nf * 16 + ccol];
            v = fmaxf(v, 0.f);
            ht[lrow * LDK + nf * 16 + ccol] = f2h(v);
        }
    }
    __syncthreads();

#pragma unroll
    for (int i = 0; i < 16; i++) {
        int row = wid * 16 + i;
        int grow = blockIdx.x * 64 + row;
        if (grow < n) {
            reinterpret_cast<uint*>(h_f16 + (size_t)grow * 128)[lane] =
                reinterpret_cast<const uint*>(&ht[row * LDK])[lane];
        }
    }
}

// ---------------- MFMA GEMM layer 2 + normalize + output GEMM ----------------

__global__ __launch_bounds__(256) void gemm2(
        const ushort* __restrict__ A1, const ushort* __restrict__ W2lP,
        const ushort* __restrict__ A2, const ushort* __restrict__ W2rP,
        const float* __restrict__ b2, const ushort* __restrict__ WmP,
        const float* __restrict__ bm, float* __restrict__ outp,
        float* __restrict__ embn, int n) {
    __shared__ ushort et[64 * LDK];   // 17.4 KB emb fp16 tile
    __shared__ float rnorm[64];
    int wid = threadIdx.x >> 6;
    int lane = threadIdx.x & 63;
    int row0 = blockIdx.x * 64 + wid * 16;
    int fr = lane & 15;
    int ko = (lane >> 4) * 8;
    int arow = row0 + fr;
    if (arow >= n) arow = n - 1;

    f32x4 acc[8];
#pragma unroll
    for (int nf = 0; nf < 8; nf++) acc[nf] = (f32x4)0.f;

    for (int seg = 0; seg < 2; ++seg) {
        const ushort* A = seg ? A2 : A1;
        const ushort* WP = seg ? W2rP : W2lP;
#pragma unroll
        for (int kg = 0; kg < 4; kg++) {
            f16x8 av = *reinterpret_cast<const f16x8*>(A + (size_t)arow * 128 + kg * 32 + ko);
#pragma unroll
            for (int nf = 0; nf < 8; nf++) {
                f16x8 bv = *reinterpret_cast<const f16x8*>(WP + (nf * 4 + kg) * 512 + lane * 8);
                acc[nf] = __builtin_amdgcn_mfma_f32_16x16x32_f16(av, bv, acc[nf], 0, 0, 0);
            }
        }
    }

    int crow = (lane >> 4) * 4;
    int ccol = lane & 15;
#pragma unroll
    for (int reg = 0; reg < 4; reg++) {
        float vv[8];
        float ss = 0.f;
#pragma unroll
        for (int nf = 0; nf < 8; nf++) {
            float v = acc[nf][reg] + b2[nf * 16 + ccol];
            vv[nf] = v;
            ss += v * v;
        }
        ss += __shfl_xor(ss, 1);
        ss += __shfl_xor(ss, 2);
        ss += __shfl_xor(ss, 4);
        ss += __shfl_xor(ss, 8);
        float inv = 1.0f / fmaxf(sqrtf(ss), 1e-12f);
        int lrow = wid * 16 + crow + reg;
#pragma unroll
        for (int nf = 0; nf < 8; nf++)
            et[lrow * LDK + nf * 16 + ccol] = f2h(vv[nf]);
        if (ccol == 0) rnorm[lrow] = inv;
    }
    __syncthreads();

#pragma unroll
    for (int i = 0; i < 16; i++) {
        int row = wid * 16 + i;
        int grow = blockIdx.x * 64 + row;
        if (grow < n) {
            float inv = rnorm[row];
            ushort2 e = reinterpret_cast<const ushort2*>(&et[row * LDK])[lane];
            float2 o;
            o.x = h2f(e.x) * inv;
            o.y = h2f(e.y) * inv;
            reinterpret_cast<float2*>(embn + (size_t)grow * 128)[lane] = o;
        }
    }

    f32x4 acc2[4];
#pragma unroll
    for (int nf = 0; nf < 4; nf++) acc2[nf] = (f32x4)0.f;
#pragma unroll
    for (int kg = 0; kg < 4; kg++) {
        f16x8 av = *reinterpret_cast<const f16x8*>(&et[(wid * 16 + fr) * LDK + kg * 32 + ko]);
#pragma unroll
        for (int nf = 0; nf < 4; nf++) {
            f16x8 bv = *reinterpret_cast<const f16x8*>(WmP + (nf * 4 + kg) * 512 + lane * 8);
            acc2[nf] = __builtin_amdgcn_mfma_f32_16x16x32_f16(av, bv, acc2[nf], 0, 0, 0);
        }
    }
#pragma unroll
    for (int reg = 0; reg < 4; reg++) {
        int grow = row0 + crow + reg;
        if (grow < n) {
#pragma unroll
            for (int nf = 0; nf < 4; nf++)
                outp[(size_t)grow * 64 + nf * 16 + ccol] = acc2[nf][reg] + bm[nf * 16 + ccol];
        }
    }
}

// ---------------- launch ----------------

extern "C" void kernel_launch(void* const* d_in, const int* in_sizes, int n_in,
                              void* d_out, int out_size, void* d_ws, size_t ws_size,
                              hipStream_t stream) {
    const float* x   = (const float*)d_in[0];
    const int*   ei  = (const int*)d_in[1];
    const float* W1l = (const float*)d_in[2];
    const float* b1  = (const float*)d_in[3];
    const float* W1r = (const float*)d_in[4];
    const float* W2l = (const float*)d_in[5];
    const float* b2  = (const float*)d_in[6];
    const float* W2r = (const float*)d_in[7];
    const float* Wm  = (const float*)d_in[8];
    const float* bm  = (const float*)d_in[9];

    const int N = N_NODES, E = N_EDGES;
    const int* src = ei;
    const int* dst = ei + E;

    char* ws = (char*)d_ws;
    int* bcnt  = (int*)ws;  ws += sizeof(int) * NB;
    int* boffs = (int*)ws;  ws += sizeof(int) * NB;
    int* gcur  = (int*)ws;  ws += sizeof(int) * NB;
    int* noffs = (int*)ws;  ws += sizeof(int) * N_NODES;
    int* ncnt  = (int*)ws;  ws += sizeof(int) * N_NODES;
    uintptr_t p0 = ((uintptr_t)ws + 255) & ~(uintptr_t)255;
    uint* bedges = (uint*)p0;
    uint* srcs_sorted = bedges + N_EDGES;
    uintptr_t p1 = ((uintptr_t)(srcs_sorted + N_EDGES) + 255) & ~(uintptr_t)255;
    ushort* mean_f16 = (ushort*)p1;                 // N*128 fp16
    ushort* x_f16    = mean_f16 + (size_t)N * 128;
    ushort* h_f16    = x_f16 + (size_t)N * 128;
    ushort* W1lP     = h_f16 + (size_t)N * 128;     // packed 128x128 fp16
    ushort* W1rP     = W1lP + 128 * 128;
    ushort* W2lP     = W1rP + 128 * 128;
    ushort* W2rP     = W2lP + 128 * 128;
    ushort* WmP      = W2rP + 128 * 128;            // packed 128x64 fp16

    float* outp = (float*)d_out;            // N x 64
    float* embn = outp + (size_t)N * 64;    // N x 128 (normalized emb)

    hipMemsetAsync(bcnt, 0, sizeof(int) * NB, stream);
    hipMemsetAsync(gcur, 0, sizeof(int) * NB, stream);

    int n4 = N * 128 / 4;                           // 3,200,000
    int prep_blocks = 256 + 12500 + 288;
    prep_all<<<prep_blocks, 256, 0, stream>>>(dst, bcnt, E, x, x_f16, n4,
                                              W1l, W1r, W2l, W2r, Wm,
                                              W1lP, W1rP, W2lP, W2rP, WmP);
    scan_buckets<<<1, 256, 0, stream>>>(bcnt, boffs);
    bucket_scatter<<<256, 256, 0, stream>>>(src, dst, boffs, gcur, bedges, E);
    sort_buckets<<<NB, 256, 0, stream>>>(bedges, boffs, bcnt,
                                         srcs_sorted, noffs, ncnt, N);

    int gblk = (N + 63) / 64;   // 1563

    // Layer 1: mean = agg(x_f16); h_f16 = relu(mean@W1l + x@W1r + b1)
    aggregate_sliced<<<NB * 4, 256, 0, stream>>>(x_f16, srcs_sorted, noffs, ncnt,
                                                 mean_f16, N);
    gemm1<<<gblk, 256, 0, stream>>>(mean_f16, W1lP, x_f16, W1rP, b1, h_f16, N);

    // Layer 2: mean = agg(h_f16); emb_n -> d_out; out = emb@Wm + bm -> d_out
    aggregate_sliced<<<NB * 4, 256, 0, stream>>>(h_f16, srcs_sorted, noffs, ncnt,
                                                 mean_f16, N);
    gemm2<<<gblk, 256, 0, stream>>>(mean_f16, W2lP, h_f16, W2rP, b2,
                                    WmP, bm, outp, embn, N);
}

// Round 16
// 283.453 us; speedup vs baseline: 1.5666x; 1.5666x over previous
//
#include <hip/hip_runtime.h>
#include <hip/hip_fp16.h>
#include <cstdint>
#include <cstddef>

#define N_NODES 100000
#define N_EDGES 1600000
#define BSH 6
#define BNODES 64
#define NB 1563          // ceil(100000/64)
#define CHUNK 2048
#define LDK 136          // LDS tile row stride in halves (272 B)

typedef _Float16 f16x8 __attribute__((ext_vector_type(8)));
typedef float f32x4 __attribute__((ext_vector_type(4)));

// ---------------- fp16 helpers ----------------

__device__ __forceinline__ float h2f(ushort u) {
    __half_raw r;
    r.x = u;
    return __half2float(__half(r));
}

__device__ __forceinline__ ushort f2h(float f) {
    __half h = __float2half(f);
    return static_cast<__half_raw>(h).x;
}

__device__ __forceinline__ void acc4(float4& a, uint2 v) {
    a.x += h2f((ushort)(v.x & 0xffff));
    a.y += h2f((ushort)(v.x >> 16));
    a.z += h2f((ushort)(v.y & 0xffff));
    a.w += h2f((ushort)(v.y >> 16));
}

// ---------------- fused prep: bucket count + cast x + PACK weights ----------------
// Packed weight layout per matrix (C cols): flat o = ((nf*4 + kg)*64 + lane)*8 + j
// holds W[k][c] with k = kg*32 + (lane>>4)*8 + j, c = nf*16 + (lane&15).

__global__ __launch_bounds__(256) void prep_all(
        const int* __restrict__ dst, int* __restrict__ bcnt, int E,
        const float* __restrict__ x, ushort* __restrict__ x_f16, int n4,
        const float* __restrict__ W1l, const float* __restrict__ W1r,
        const float* __restrict__ W2l, const float* __restrict__ W2r,
        const float* __restrict__ Wm,
        ushort* __restrict__ W1lP, ushort* __restrict__ W1rP,
        ushort* __restrict__ W2lP, ushort* __restrict__ W2rP,
        ushort* __restrict__ WmP) {
    int bid = blockIdx.x;
    if (bid < 256) {
        __shared__ int lh[NB];
        for (int i = threadIdx.x; i < NB; i += 256) lh[i] = 0;
        __syncthreads();
        for (int e = bid * 256 + threadIdx.x; e < E; e += 256 * 256)
            atomicAdd(&lh[dst[e] >> BSH], 1);
        __syncthreads();
        for (int i = threadIdx.x; i < NB; i += 256) {
            int v = lh[i];
            if (v) atomicAdd(&bcnt[i], v);
        }
    } else if (bid < 256 + 12500) {
        int i = (bid - 256) * 256 + threadIdx.x;
        if (i < n4) {
            float4 v = reinterpret_cast<const float4*>(x)[i];
            ushort4 o;
            o.x = f2h(v.x);
            o.y = f2h(v.y);
            o.z = f2h(v.z);
            o.w = f2h(v.w);
            reinterpret_cast<ushort4*>(x_f16)[i] = o;
        }
    } else {
        int t = (bid - (256 + 12500)) * 256 + threadIdx.x;
        if (t < 65536) {            // 4 matrices of 128x128
            int wsel = t >> 14;
            int o = t & 16383;
            const float* srcs[4] = {W1l, W1r, W2l, W2r};
            ushort* dsts[4] = {W1lP, W1rP, W2lP, W2rP};
            int j = o & 7;
            int lane = (o >> 3) & 63;
            int kg = (o >> 9) & 3;
            int nf = o >> 11;
            int k = kg * 32 + (lane >> 4) * 8 + j;
            int c = nf * 16 + (lane & 15);
            dsts[wsel][o] = f2h(srcs[wsel][k * 128 + c]);
        } else if (t < 65536 + 8192) {  // Wm: 128x64
            int o = t - 65536;
            int j = o & 7;
            int lane = (o >> 3) & 63;
            int kg = (o >> 9) & 3;
            int nf = o >> 11;           // < 4
            int k = kg * 32 + (lane >> 4) * 8 + j;
            int c = nf * 16 + (lane & 15);
            WmP[o] = f2h(Wm[k * 64 + c]);
        }
    }
}

// ---------------- scatter with inlined bucket-offset scan ----------------
// Each block computes the exclusive scan of bcnt locally (LDS); block 0 also
// publishes it to global boffs for the aggregate kernels.

__global__ __launch_bounds__(256) void bucket_scatter(
        const int* __restrict__ src, const int* __restrict__ dst,
        const int* __restrict__ bcnt, int* __restrict__ gcur,
        uint* __restrict__ bedges, int* __restrict__ boffs, int E) {
    __shared__ int lh[NB];
    __shared__ int lbase[NB];
    __shared__ int bo[NB];
    __shared__ int sdata[256];
    int tid = threadIdx.x;

    // inline exclusive scan of bcnt -> bo
    {
        int v[8];
        int s = 0;
#pragma unroll
        for (int i = 0; i < 8; i++) {
            int idx = tid * 8 + i;
            v[i] = (idx < NB) ? bcnt[idx] : 0;
            s += v[i];
        }
        sdata[tid] = s;
        __syncthreads();
        int acc = s;
        for (int off = 1; off < 256; off <<= 1) {
            int t = (tid >= off) ? sdata[tid - off] : 0;
            __syncthreads();
            acc += t;
            sdata[tid] = acc;
            __syncthreads();
        }
        int excl = acc - s;
#pragma unroll
        for (int i = 0; i < 8; i++) {
            int idx = tid * 8 + i;
            if (idx < NB) bo[idx] = excl;
            excl += v[i];
        }
    }
    __syncthreads();
    if (blockIdx.x == 0) {
        for (int i = tid; i < NB; i += 256) boffs[i] = bo[i];
    }

    int nwg = gridDim.x;
    int chunk = (E + nwg - 1) / nwg;
    int e0 = blockIdx.x * chunk;
    int e1 = e0 + chunk;
    if (e1 > E) e1 = E;
    for (int i = tid; i < NB; i += 256) lh[i] = 0;
    __syncthreads();
    for (int e = e0 + tid; e < e1; e += 256)
        atomicAdd(&lh[dst[e] >> BSH], 1);
    __syncthreads();
    for (int i = tid; i < NB; i += 256) {
        int v = lh[i];
        lbase[i] = v ? (bo[i] + atomicAdd(&gcur[i], v)) : 0;
    }
    __syncthreads();
    for (int i = tid; i < NB; i += 256) lh[i] = 0;  // reuse as local cursor
    __syncthreads();
    int e = e0 + tid;
#pragma unroll 1
    for (; e + 3 * 256 < e1; e += 4 * 256) {
        int d0 = dst[e + 0 * 256], s0 = src[e + 0 * 256];
        int d1 = dst[e + 1 * 256], s1 = src[e + 1 * 256];
        int d2 = dst[e + 2 * 256], s2 = src[e + 2 * 256];
        int d3 = dst[e + 3 * 256], s3 = src[e + 3 * 256];
        int b0 = d0 >> BSH, b1 = d1 >> BSH, b2 = d2 >> BSH, b3 = d3 >> BSH;
        int r0 = atomicAdd(&lh[b0], 1);
        int r1 = atomicAdd(&lh[b1], 1);
        int r2 = atomicAdd(&lh[b2], 1);
        int r3 = atomicAdd(&lh[b3], 1);
        bedges[lbase[b0] + r0] = ((uint)(d0 & (BNODES - 1)) << 17) | (uint)s0;
        bedges[lbase[b1] + r1] = ((uint)(d1 & (BNODES - 1)) << 17) | (uint)s1;
        bedges[lbase[b2] + r2] = ((uint)(d2 & (BNODES - 1)) << 17) | (uint)s2;
        bedges[lbase[b3] + r3] = ((uint)(d3 & (BNODES - 1)) << 17) | (uint)s3;
    }
    for (; e < e1; e += 256) {
        int d = dst[e];
        int b = d >> BSH;
        int r = atomicAdd(&lh[b], 1);
        bedges[lbase[b] + r] = ((uint)(d & (BNODES - 1)) << 17) | (uint)src[e];
    }
}

// ---------------- bucketed mean aggregation (R9-proven, standalone) ----------------

__global__ __launch_bounds__(512) void aggregate_bucket(
        const ushort* __restrict__ F, const uint* __restrict__ bedges,
        const int* __restrict__ boffs, const int* __restrict__ bcnt,
        ushort* __restrict__ out, int n) {
    int b = blockIdx.x;
    int beg = boffs[b];
    int m = bcnt[b];
    int node0 = b << BSH;
    int nNodes = n - node0;
    if (nNodes > BNODES) nNodes = BNODES;
    __shared__ uint ls[CHUNK];
    __shared__ int lh[BNODES];
    __shared__ int lofs[BNODES];
    __shared__ int pcnt[BNODES];
    int tid = threadIdx.x;
    int wid = tid >> 6;     // 0..7
    int lane = tid & 63;
    int hw = lane >> 5;     // half-wave 0/1
    int cl = lane & 31;     // channels cl*4 .. cl*4+3

    float4 acc[8];
#pragma unroll
    for (int i = 0; i < 8; i++) acc[i] = make_float4(0.f, 0.f, 0.f, 0.f);
    if (tid < BNODES) pcnt[tid] = 0;

    for (int base = 0; base < m; base += CHUNK) {
        int mm = m - base;
        if (mm > CHUNK) mm = CHUNK;
        __syncthreads();
        if (tid < BNODES) lh[tid] = 0;
        __syncthreads();
        for (int i = tid; i < mm; i += 512)
            atomicAdd(&lh[bedges[beg + base + i] >> 17], 1);
        __syncthreads();
        if (tid < BNODES) {   // wave 0 only
            int v = lh[tid];
            int s = v;
#pragma unroll
            for (int off = 1; off < 64; off <<= 1) {
                int t = __shfl_up(s, off);
                if (lane >= off) s += t;
            }
            lofs[tid] = s - v;   // exclusive
            pcnt[tid] += v;
            lh[tid] = 0;         // reuse as cursor
        }
        __syncthreads();
        for (int i = tid; i < mm; i += 512) {
            uint p = bedges[beg + base + i];
            int k = p >> 17;
            int r = atomicAdd(&lh[k], 1);
            ls[lofs[k] + r] = p;
        }
        __syncthreads();
#pragma unroll
        for (int ki = 0; ki < 8; ki++) {
            int k = wid * 8 + ki;
            int s0 = lofs[k];
            int ck = lh[k];
            int j = hw;
            for (; j + 6 < ck; j += 8) {
                uint p0 = ls[s0 + j + 0] & 0x1FFFFu;
                uint p1 = ls[s0 + j + 2] & 0x1FFFFu;
                uint p2 = ls[s0 + j + 4] & 0x1FFFFu;
                uint p3 = ls[s0 + j + 6] & 0x1FFFFu;
                uint2 v0 = *reinterpret_cast<const uint2*>(F + (size_t)p0 * 128 + cl * 4);
                uint2 v1 = *reinterpret_cast<const uint2*>(F + (size_t)p1 * 128 + cl * 4);
                uint2 v2 = *reinterpret_cast<const uint2*>(F + (size_t)p2 * 128 + cl * 4);
                uint2 v3 = *reinterpret_cast<const uint2*>(F + (size_t)p3 * 128 + cl * 4);
                acc4(acc[ki], v0);
                acc4(acc[ki], v1);
                acc4(acc[ki], v2);
                acc4(acc[ki], v3);
            }
            for (; j < ck; j += 2) {
                uint p = ls[s0 + j] & 0x1FFFFu;
                uint2 v = *reinterpret_cast<const uint2*>(F + (size_t)p * 128 + cl * 4);
                acc4(acc[ki], v);
            }
        }
    }
    __syncthreads();
#pragma unroll
    for (int ki = 0; ki < 8; ki++) {
        acc[ki].x += __shfl_xor(acc[ki].x, 32);
        acc[ki].y += __shfl_xor(acc[ki].y, 32);
        acc[ki].z += __shfl_xor(acc[ki].z, 32);
        acc[ki].w += __shfl_xor(acc[ki].w, 32);
    }
    if (hw == 0) {
#pragma unroll
        for (int ki = 0; ki < 8; ki++) {
            int k = wid * 8 + ki;
            if (k < nNodes) {
                float inv = 1.0f / fmaxf((float)pcnt[k], 1.0f);
                uint2 o;
                o.x = (uint)f2h(acc[ki].x * inv) | ((uint)f2h(acc[ki].y * inv) << 16);
                o.y = (uint)f2h(acc[ki].z * inv) | ((uint)f2h(acc[ki].w * inv) << 16);
                *reinterpret_cast<uint2*>(out + (size_t)(node0 + k) * 128 + cl * 4) = o;
            }
        }
    }
}

// ---------------- MFMA GEMM layer 1: 16-row waves, packed weights ----------------
// Block = 64 rows (4 waves x 16), grid 1563. h = relu(mean@W1l + x@W1r + b1).

__global__ __launch_bounds__(256) void gemm1(
        const ushort* __restrict__ A1, const ushort* __restrict__ W1lP,
        const ushort* __restrict__ A2, const ushort* __restrict__ W1rP,
        const float* __restrict__ b1, ushort* __restrict__ h_f16, int n) {
    __shared__ ushort ht[64 * LDK];   // 17.4 KB h fp16 tile
    int wid = threadIdx.x >> 6;
    int lane = threadIdx.x & 63;
    int row0 = blockIdx.x * 64 + wid * 16;
    int fr = lane & 15;
    int ko = (lane >> 4) * 8;
    int arow = row0 + fr;
    if (arow >= n) arow = n - 1;

    f32x4 acc[8];
#pragma unroll
    for (int nf = 0; nf < 8; nf++) acc[nf] = (f32x4)0.f;

    for (int seg = 0; seg < 2; ++seg) {
        const ushort* A = seg ? A2 : A1;
        const ushort* WP = seg ? W1rP : W1lP;
#pragma unroll
        for (int kg = 0; kg < 4; kg++) {
            f16x8 av = *reinterpret_cast<const f16x8*>(A + (size_t)arow * 128 + kg * 32 + ko);
#pragma unroll
            for (int nf = 0; nf < 8; nf++) {
                f16x8 bv = *reinterpret_cast<const f16x8*>(WP + (nf * 4 + kg) * 512 + lane * 8);
                acc[nf] = __builtin_amdgcn_mfma_f32_16x16x32_f16(av, bv, acc[nf], 0, 0, 0);
            }
        }
    }

    int crow = (lane >> 4) * 4;
    int ccol = lane & 15;
#pragma unroll
    for (int reg = 0; reg < 4; reg++) {
        int lrow = wid * 16 + crow + reg;
#pragma unroll
        for (int nf = 0; nf < 8; nf++) {
            float v = acc[nf][reg] + b1[nf * 16 + ccol];
            v = fmaxf(v, 0.f);
            ht[lrow * LDK + nf * 16 + ccol] = f2h(v);
        }
    }
    __syncthreads();

#pragma unroll
    for (int i = 0; i < 16; i++) {
        int row = wid * 16 + i;
        int grow = blockIdx.x * 64 + row;
        if (grow < n) {
            reinterpret_cast<uint*>(h_f16 + (size_t)grow * 128)[lane] =
                reinterpret_cast<const uint*>(&ht[row * LDK])[lane];
        }
    }
}

// ---------------- MFMA GEMM layer 2 + normalize + output GEMM ----------------

__global__ __launch_bounds__(256) void gemm2(
        const ushort* __restrict__ A1, const ushort* __restrict__ W2lP,
        const ushort* __restrict__ A2, const ushort* __restrict__ W2rP,
        const float* __restrict__ b2, const ushort* __restrict__ WmP,
        const float* __restrict__ bm, float* __restrict__ outp,
        float* __restrict__ embn, int n) {
    __shared__ ushort et[64 * LDK];   // 17.4 KB emb fp16 tile
    __shared__ float rnorm[64];
    int wid = threadIdx.x >> 6;
    int lane = threadIdx.x & 63;
    int row0 = blockIdx.x * 64 + wid * 16;
    int fr = lane & 15;
    int ko = (lane >> 4) * 8;
    int arow = row0 + fr;
    if (arow >= n) arow = n - 1;

    f32x4 acc[8];
#pragma unroll
    for (int nf = 0; nf < 8; nf++) acc[nf] = (f32x4)0.f;

    for (int seg = 0; seg < 2; ++seg) {
        const ushort* A = seg ? A2 : A1;
        const ushort* WP = seg ? W2rP : W2lP;
#pragma unroll
        for (int kg = 0; kg < 4; kg++) {
            f16x8 av = *reinterpret_cast<const f16x8*>(A + (size_t)arow * 128 + kg * 32 + ko);
#pragma unroll
            for (int nf = 0; nf < 8; nf++) {
                f16x8 bv = *reinterpret_cast<const f16x8*>(WP + (nf * 4 + kg) * 512 + lane * 8);
                acc[nf] = __builtin_amdgcn_mfma_f32_16x16x32_f16(av, bv, acc[nf], 0, 0, 0);
            }
        }
    }

    int crow = (lane >> 4) * 4;
    int ccol = lane & 15;
#pragma unroll
    for (int reg = 0; reg < 4; reg++) {
        float vv[8];
        float ss = 0.f;
#pragma unroll
        for (int nf = 0; nf < 8; nf++) {
            float v = acc[nf][reg] + b2[nf * 16 + ccol];
            vv[nf] = v;
            ss += v * v;
        }
        ss += __shfl_xor(ss, 1);
        ss += __shfl_xor(ss, 2);
        ss += __shfl_xor(ss, 4);
        ss += __shfl_xor(ss, 8);
        float inv = 1.0f / fmaxf(sqrtf(ss), 1e-12f);
        int lrow = wid * 16 + crow + reg;
#pragma unroll
        for (int nf = 0; nf < 8; nf++)
            et[lrow * LDK + nf * 16 + ccol] = f2h(vv[nf]);
        if (ccol == 0) rnorm[lrow] = inv;
    }
    __syncthreads();

#pragma unroll
    for (int i = 0; i < 16; i++) {
        int row = wid * 16 + i;
        int grow = blockIdx.x * 64 + row;
        if (grow < n) {
            float inv = rnorm[row];
            ushort2 e = reinterpret_cast<const ushort2*>(&et[row * LDK])[lane];
            float2 o;
            o.x = h2f(e.x) * inv;
            o.y = h2f(e.y) * inv;
            reinterpret_cast<float2*>(embn + (size_t)grow * 128)[lane] = o;
        }
    }

    f32x4 acc2[4];
#pragma unroll
    for (int nf = 0; nf < 4; nf++) acc2[nf] = (f32x4)0.f;
#pragma unroll
    for (int kg = 0; kg < 4; kg++) {
        f16x8 av = *reinterpret_cast<const f16x8*>(&et[(wid * 16 + fr) * LDK + kg * 32 + ko]);
#pragma unroll
        for (int nf = 0; nf < 4; nf++) {
            f16x8 bv = *reinterpret_cast<const f16x8*>(WmP + (nf * 4 + kg) * 512 + lane * 8);
            acc2[nf] = __builtin_amdgcn_mfma_f32_16x16x32_f16(av, bv, acc2[nf], 0, 0, 0);
        }
    }
#pragma unroll
    for (int reg = 0; reg < 4; reg++) {
        int grow = row0 + crow + reg;
        if (grow < n) {
#pragma unroll
            for (int nf = 0; nf < 4; nf++)
                outp[(size_t)grow * 64 + nf * 16 + ccol] = acc2[nf][reg] + bm[nf * 16 + ccol];
        }
    }
}

// ---------------- launch ----------------

extern "C" void kernel_launch(void* const* d_in, const int* in_sizes, int n_in,
                              void* d_out, int out_size, void* d_ws, size_t ws_size,
                              hipStream_t stream) {
    const float* x   = (const float*)d_in[0];
    const int*   ei  = (const int*)d_in[1];
    const float* W1l = (const float*)d_in[2];
    const float* b1  = (const float*)d_in[3];
    const float* W1r = (const float*)d_in[4];
    const float* W2l = (const float*)d_in[5];
    const float* b2  = (const float*)d_in[6];
    const float* W2r = (const float*)d_in[7];
    const float* Wm  = (const float*)d_in[8];
    const float* bm  = (const float*)d_in[9];

    const int N = N_NODES, E = N_EDGES;
    const int* src = ei;
    const int* dst = ei + E;

    char* ws = (char*)d_ws;
    int* bcnt  = (int*)ws;  ws += sizeof(int) * NB;
    int* boffs = (int*)ws;  ws += sizeof(int) * NB;
    int* gcur  = (int*)ws;  ws += sizeof(int) * NB;
    uintptr_t p0 = ((uintptr_t)ws + 255) & ~(uintptr_t)255;
    uint* bedges = (uint*)p0;
    uintptr_t p1 = ((uintptr_t)(bedges + N_EDGES) + 255) & ~(uintptr_t)255;
    ushort* mean_f16 = (ushort*)p1;                 // N*128 fp16
    ushort* x_f16    = mean_f16 + (size_t)N * 128;
    ushort* h_f16    = x_f16 + (size_t)N * 128;
    ushort* W1lP     = h_f16 + (size_t)N * 128;     // packed 128x128 fp16
    ushort* W1rP     = W1lP + 128 * 128;
    ushort* W2lP     = W1rP + 128 * 128;
    ushort* W2rP     = W2lP + 128 * 128;
    ushort* WmP      = W2rP + 128 * 128;            // packed 128x64 fp16

    float* outp = (float*)d_out;            // N x 64
    float* embn = outp + (size_t)N * 64;    // N x 128 (normalized emb)

    hipMemsetAsync(bcnt, 0, sizeof(int) * NB, stream);
    hipMemsetAsync(gcur, 0, sizeof(int) * NB, stream);

    int n4 = N * 128 / 4;                           // 3,200,000
    int prep_blocks = 256 + 12500 + 288;
    prep_all<<<prep_blocks, 256, 0, stream>>>(dst, bcnt, E, x, x_f16, n4,
                                              W1l, W1r, W2l, W2r, Wm,
                                              W1lP, W1rP, W2lP, W2rP, WmP);
    bucket_scatter<<<256, 256, 0, stream>>>(src, dst, bcnt, gcur, bedges, boffs, E);

    int gblk = (N + 63) / 64;   // 1563

    // Layer 1: mean = agg(x_f16); h_f16 = relu(mean@W1l + x@W1r + b1)
    aggregate_bucket<<<NB, 512, 0, stream>>>(x_f16, bedges, boffs, bcnt, mean_f16, N);
    gemm1<<<gblk, 256, 0, stream>>>(mean_f16, W1lP, x_f16, W1rP, b1, h_f16, N);

    // Layer 2: mean = agg(h_f16); emb_n -> d_out; out = emb@Wm + bm -> d_out
    aggregate_bucket<<<NB, 512, 0, stream>>>(h_f16, bedges, boffs, bcnt, mean_f16, N);
    gemm2<<<gblk, 256, 0, stream>>>(mean_f16, W2lP, h_f16, W2rP, b2,
                                    WmP, bm, outp, embn, N);
}